// Round 4
// baseline (59224.219 us; speedup 1.0000x reference)
//
#include <hip/hip_runtime.h>

#define B_ 512
#define T_ 256
#define D_ 128
#define H_ 512

typedef __bf16 bf16x8 __attribute__((ext_vector_type(8)));
typedef float f32x4 __attribute__((ext_vector_type(4)));

__device__ __forceinline__ float sigm(float x) { return 1.f / (1.f + __expf(-x)); }
__device__ __forceinline__ float tanh_(float x) { return 2.f / (1.f + __expf(-2.f * x)) - 1.f; }

__device__ __forceinline__ void split2(float v, __bf16& hi, __bf16& lo) {
    hi = (__bf16)v;
    lo = (__bf16)(v - (float)hi);
}

// ---------------- weight convert: fp32 -> split bf16 (hi+lo), transposed to [N][K] ----------------
__global__ void k_convert(const float* __restrict__ k0, const float* __restrict__ r0,
                          const float* __restrict__ k1, const float* __restrict__ r1,
                          const float* __restrict__ W,
                          __bf16* __restrict__ wB0Th, __bf16* __restrict__ wB0Tl,  // [2048][640]
                          __bf16* __restrict__ wB1Th, __bf16* __restrict__ wB1Tl,  // [2048][1024]
                          __bf16* __restrict__ wWTh,  __bf16* __restrict__ wWTl)   // [128][512]
{
    int tid = blockIdx.x * blockDim.x + threadIdx.x;
    int nth = gridDim.x * blockDim.x;
    for (int idx = tid; idx < 640 * 2048; idx += nth) {
        int k = idx >> 11, n = idx & 2047;
        float v = (k < 128) ? k0[k * 2048 + n] : r0[(k - 128) * 2048 + n];
        split2(v, wB0Th[n * 640 + k], wB0Tl[n * 640 + k]);
    }
    for (int idx = tid; idx < 1024 * 2048; idx += nth) {
        int k = idx >> 11, n = idx & 2047;
        float v = (k < 512) ? k1[k * 2048 + n] : r1[(k - 512) * 2048 + n];
        split2(v, wB1Th[n * 1024 + k], wB1Tl[n * 1024 + k]);
    }
    for (int idx = tid; idx < 512 * 128; idx += nth) {
        int k = idx >> 7, n = idx & 127;
        split2(W[k * 128 + n], wWTh[n * 512 + k], wWTl[n * 512 + k]);
    }
}

// ---------------- init: cur = x[:,0,:] (split), zero h/c state, zero barrier flags ------------
__global__ void k_init(const float* __restrict__ x,
                       __bf16* __restrict__ curh, __bf16* __restrict__ curl,
                       __bf16* __restrict__ h0ah, __bf16* __restrict__ h0al,
                       __bf16* __restrict__ h0bh, __bf16* __restrict__ h0bl,
                       __bf16* __restrict__ h1ah, __bf16* __restrict__ h1al,
                       __bf16* __restrict__ h1bh, __bf16* __restrict__ h1bl,
                       float* __restrict__ c0, float* __restrict__ c1,
                       int* __restrict__ flags)
{
    int tid = blockIdx.x * blockDim.x + threadIdx.x;
    int nth = gridDim.x * blockDim.x;
    if (tid < 256) flags[tid] = 0;
    for (int idx = tid; idx < B_ * D_; idx += nth) {
        int b = idx >> 7, d = idx & 127;
        split2(x[b * (T_ * D_) + d], curh[idx], curl[idx]);  // t=0: missing stays 128.0 exactly
    }
    for (int idx = tid; idx < B_ * H_; idx += nth) {
        h0ah[idx] = (__bf16)0.f; h0al[idx] = (__bf16)0.f;
        h0bh[idx] = (__bf16)0.f; h0bl[idx] = (__bf16)0.f;
        h1ah[idx] = (__bf16)0.f; h1al[idx] = (__bf16)0.f;
        h1bh[idx] = (__bf16)0.f; h1bl[idx] = (__bf16)0.f;
        c0[idx] = 0.f; c1[idx] = 0.f;
    }
}

// ---------------- grid barrier: per-WG flag slot, monotonic epoch ----------------
__device__ __forceinline__ void gbar(int* flags, int k) {
    __syncthreads();                 // WG work done
    __threadfence();                 // each thread: flush writes device-wide (L2 wb)
    __syncthreads();                 // all fences done
    int tid = threadIdx.x;
    if (tid == 0)
        __hip_atomic_store(&flags[blockIdx.x], k, __ATOMIC_RELAXED, __HIP_MEMORY_SCOPE_AGENT);
    if (tid < 256)
        while (__hip_atomic_load(&flags[tid], __ATOMIC_RELAXED, __HIP_MEMORY_SCOPE_AGENT) < k)
            __builtin_amdgcn_s_sleep(2);
    __syncthreads();                 // all observed
    __threadfence();                 // invalidate stale L1/L2 before reading remote data
}

// ---------------- one LSTM layer phase (same structure as r3 k_layer) ----------------
template <int KTOT, int K1>
__device__ __forceinline__ void layer_phase(
    const __bf16* __restrict__ A1h, const __bf16* __restrict__ A1l, int lda1,
    const __bf16* __restrict__ A2h, const __bf16* __restrict__ A2l, int lda2,
    const __bf16* __restrict__ BTh, const __bf16* __restrict__ BTl,
    const float* __restrict__ bias,
    float* __restrict__ cstate,
    __bf16* __restrict__ houth, __bf16* __restrict__ houtl,
    float* __restrict__ hout_f32,
    int j0, int m0,
    __bf16* sAh, __bf16* sAl, __bf16* sBh, __bf16* sBl, float* szred)
{
    constexpr int LSTR = 72;
    const int tid = threadIdx.x;
    const int lane = tid & 63;
    const int wave = tid >> 6;
    const int wpair = wave >> 1;
    const int ksub = wave & 1;

    const int srow = tid >> 3;
    const int skc = (tid & 7) << 3;
    const int bgrow = (srow >> 4) * 512 + j0 + (srow & 15);

    uint4 pAh, pAl, pBh, pBl;
    auto loadA = [&](int kb) {
        int k = kb + skc;
        const __bf16 *ah, *al; size_t off;
        if (k < K1) { ah = A1h; al = A1l; off = (size_t)(m0 + srow) * lda1 + k; }
        else        { ah = A2h; al = A2l; off = (size_t)(m0 + srow) * lda2 + (k - K1); }
        pAh = *reinterpret_cast<const uint4*>(ah + off);
        pAl = *reinterpret_cast<const uint4*>(al + off);
    };
    auto loadB = [&](int kb) {
        size_t off = (size_t)bgrow * KTOT + kb + skc;
        pBh = *reinterpret_cast<const uint4*>(BTh + off);
        pBl = *reinterpret_cast<const uint4*>(BTl + off);
    };

    loadA(0); loadB(0);

    f32x4 acc[4] = {};
    const int aidx = (wpair * 16 + (lane & 15)) * LSTR + ksub * 32 + ((lane >> 4) << 3);
    const int kf = ksub * 32 + ((lane >> 4) << 3);

    for (int kb = 0; kb < KTOT; kb += 64) {
        __syncthreads();
        *reinterpret_cast<uint4*>(&sAh[srow * LSTR + skc]) = pAh;
        *reinterpret_cast<uint4*>(&sAl[srow * LSTR + skc]) = pAl;
        *reinterpret_cast<uint4*>(&sBh[srow * LSTR + skc]) = pBh;
        *reinterpret_cast<uint4*>(&sBl[srow * LSTR + skc]) = pBl;
        if (kb + 64 < KTOT) { loadA(kb + 64); loadB(kb + 64); }
        __syncthreads();
        bf16x8 a_h = *reinterpret_cast<const bf16x8*>(&sAh[aidx]);
        bf16x8 a_l = *reinterpret_cast<const bf16x8*>(&sAl[aidx]);
#pragma unroll
        for (int g = 0; g < 4; ++g) {
            int bi = (g * 16 + (lane & 15)) * LSTR + kf;
            bf16x8 b_h = *reinterpret_cast<const bf16x8*>(&sBh[bi]);
            bf16x8 b_l = *reinterpret_cast<const bf16x8*>(&sBl[bi]);
            acc[g] = __builtin_amdgcn_mfma_f32_16x16x32_bf16(a_h, b_h, acc[g], 0, 0, 0);
            acc[g] = __builtin_amdgcn_mfma_f32_16x16x32_bf16(a_h, b_l, acc[g], 0, 0, 0);
            acc[g] = __builtin_amdgcn_mfma_f32_16x16x32_bf16(a_l, b_h, acc[g], 0, 0, 0);
        }
    }

    if (ksub == 1) {
#pragma unroll
        for (int g = 0; g < 4; ++g)
            *reinterpret_cast<f32x4*>(&szred[(wpair * 64 + lane) * 20 + g * 4]) = acc[g];
    }
    __syncthreads();
    if (ksub == 0) {
        const int col = j0 + (lane & 15);
        const float* zr = &szred[(wpair * 64 + lane) * 20];
#pragma unroll
        for (int r = 0; r < 4; ++r) {
            int row = m0 + wpair * 16 + ((lane >> 4) << 2) + r;
            float zi = acc[0][r] + zr[0 + r] + bias[col];
            float zf = acc[1][r] + zr[4 + r] + bias[512 + col];
            float zg = acc[2][r] + zr[8 + r] + bias[1024 + col];
            float zo = acc[3][r] + zr[12 + r] + bias[1536 + col];
            float gi = sigm(zi), gf = sigm(zf), gg = tanh_(zg), go = sigm(zo);
            int cidx = row * H_ + col;
            float c = gf * cstate[cidx] + gi * gg;
            cstate[cidx] = c;
            float h = go * tanh_(c);
            split2(h, houth[cidx], houtl[cidx]);
            if (hout_f32) hout_f32[cidx] = h;
        }
    }
}

// ---------------- pred phase: one 16x16 tile per WG, wave 0, direct-load MFMA ----------------
__device__ __forceinline__ void pred_phase(
    const __bf16* __restrict__ h1ph, const __bf16* __restrict__ h1pl,
    const __bf16* __restrict__ WTh, const __bf16* __restrict__ WTl,
    const float* __restrict__ bout, const float* __restrict__ x, int t,
    __bf16* __restrict__ curh, __bf16* __restrict__ curl,
    float* __restrict__ outPred, int wg)
{
    const int tid = threadIdx.x;
    if (tid >= 64) return;           // wave 0 only; no syncthreads inside
    const int l = tid;
    const int pr = wg >> 3;          // row tile 0..31
    const int pc = wg & 7;           // col tile 0..7
    const int arow = (pr * 16 + (l & 15)) * 512;
    const int brow = (pc * 16 + (l & 15)) * 512;
    const int kc = (l >> 4) << 3;

    f32x4 acc = {};
#pragma unroll 4
    for (int kb = 0; kb < 512; kb += 32) {
        bf16x8 ah = *reinterpret_cast<const bf16x8*>(h1ph + arow + kb + kc);
        bf16x8 al = *reinterpret_cast<const bf16x8*>(h1pl + arow + kb + kc);
        bf16x8 bh = *reinterpret_cast<const bf16x8*>(WTh + brow + kb + kc);
        bf16x8 bl = *reinterpret_cast<const bf16x8*>(WTl + brow + kb + kc);
        acc = __builtin_amdgcn_mfma_f32_16x16x32_bf16(ah, bh, acc, 0, 0, 0);
        acc = __builtin_amdgcn_mfma_f32_16x16x32_bf16(ah, bl, acc, 0, 0, 0);
        acc = __builtin_amdgcn_mfma_f32_16x16x32_bf16(al, bh, acc, 0, 0, 0);
    }

    const int col = pc * 16 + (l & 15);
#pragma unroll
    for (int r = 0; r < 4; ++r) {
        int b = pr * 16 + ((l >> 4) << 2) + r;
        float pred = acc[r] + bout[col];
        float xv = x[(b * T_ + t) * D_ + col];
        float cv = (xv == 128.0f) ? pred : xv;
        int ci = b * D_ + col;
        split2(cv, curh[ci], curl[ci]);
        outPred[((size_t)b * (T_ - 1) + (t - 1)) * D_ + col] = pred;
    }
}

// ---------------- persistent kernel: whole T-loop with grid barriers ----------------
struct KArgs {
    const float* x;
    const __bf16 *wB0Th, *wB0Tl, *wB1Th, *wB1Tl, *wWTh, *wWTl;
    const float *b0, *b1, *bo;
    __bf16 *curh, *curl;
    __bf16 *h0h0, *h0l0, *h0h1, *h0l1;
    __bf16 *h1h0, *h1l0, *h1h1, *h1l1;
    float *c0, *c1;
    float *outPred, *lastcell;
    int* flags;
};

__global__ __launch_bounds__(512) void k_persistent(KArgs a)
{
    __shared__ __align__(16) __bf16 sAh[64 * 72], sAl[64 * 72];
    __shared__ __align__(16) __bf16 sBh[64 * 72], sBl[64 * 72];
    __shared__ __align__(16) float szred[4 * 64 * 20];

    const int wg = blockIdx.x;
    const int j0 = (wg & 31) * 16;
    const int m0 = (wg >> 5) * 64;

    __bf16* h0h[2] = { a.h0h0, a.h0h1 };
    __bf16* h0l[2] = { a.h0l0, a.h0l1 };
    __bf16* h1h[2] = { a.h1h0, a.h1h1 };
    __bf16* h1l[2] = { a.h1l0, a.h1l1 };

    int bk = 0;
    for (int t = 0; t < T_; ++t) {
        int cu = t & 1, pv = cu ^ 1;
        if (t > 0) {
            pred_phase(h1h[pv], h1l[pv], a.wWTh, a.wWTl, a.bo, a.x, t,
                       a.curh, a.curl, a.outPred, wg);
            gbar(a.flags, ++bk);
        }
        layer_phase<640, 128>(a.curh, a.curl, D_, h0h[pv], h0l[pv], H_,
                              a.wB0Th, a.wB0Tl, a.b0, a.c0,
                              h0h[cu], h0l[cu], nullptr, j0, m0,
                              sAh, sAl, sBh, sBl, szred);
        gbar(a.flags, ++bk);
        layer_phase<1024, 512>(h0h[cu], h0l[cu], H_, h1h[pv], h1l[pv], H_,
                               a.wB1Th, a.wB1Tl, a.b1, a.c1,
                               h1h[cu], h1l[cu],
                               (t == T_ - 1) ? a.lastcell : nullptr, j0, m0,
                               sAh, sAl, sBh, sBl, szred);
        gbar(a.flags, ++bk);
    }
}

extern "C" void kernel_launch(void* const* d_in, const int* in_sizes, int n_in,
                              void* d_out, int out_size, void* d_ws, size_t ws_size,
                              hipStream_t stream)
{
    const float* x  = (const float*)d_in[0];
    const float* k0 = (const float*)d_in[1];
    const float* r0 = (const float*)d_in[2];
    const float* b0 = (const float*)d_in[3];
    const float* k1 = (const float*)d_in[4];
    const float* r1 = (const float*)d_in[5];
    const float* b1 = (const float*)d_in[6];
    const float* W  = (const float*)d_in[7];
    const float* bo = (const float*)d_in[8];
    float* out = (float*)d_out;

    char* ws = (char*)d_ws;
    size_t off = 0;
    auto alloc = [&](size_t bytes) { void* p = ws + off; off += (bytes + 255) & ~255ull; return p; };
    __bf16* wB0Th = (__bf16*)alloc((size_t)2048 * 640 * 2);
    __bf16* wB0Tl = (__bf16*)alloc((size_t)2048 * 640 * 2);
    __bf16* wB1Th = (__bf16*)alloc((size_t)2048 * 1024 * 2);
    __bf16* wB1Tl = (__bf16*)alloc((size_t)2048 * 1024 * 2);
    __bf16* wWTh  = (__bf16*)alloc((size_t)128 * 512 * 2);
    __bf16* wWTl  = (__bf16*)alloc((size_t)128 * 512 * 2);
    __bf16* curh  = (__bf16*)alloc((size_t)B_ * D_ * 2);
    __bf16* curl  = (__bf16*)alloc((size_t)B_ * D_ * 2);
    __bf16* h0h[2] = { (__bf16*)alloc((size_t)B_ * H_ * 2), (__bf16*)alloc((size_t)B_ * H_ * 2) };
    __bf16* h0l[2] = { (__bf16*)alloc((size_t)B_ * H_ * 2), (__bf16*)alloc((size_t)B_ * H_ * 2) };
    __bf16* h1h[2] = { (__bf16*)alloc((size_t)B_ * H_ * 2), (__bf16*)alloc((size_t)B_ * H_ * 2) };
    __bf16* h1l[2] = { (__bf16*)alloc((size_t)B_ * H_ * 2), (__bf16*)alloc((size_t)B_ * H_ * 2) };
    float* c0 = (float*)alloc((size_t)B_ * H_ * 4);
    float* c1 = (float*)alloc((size_t)B_ * H_ * 4);
    int* flags = (int*)alloc(256 * sizeof(int));

    k_convert<<<2048, 256, 0, stream>>>(k0, r0, k1, r1, W, wB0Th, wB0Tl, wB1Th, wB1Tl, wWTh, wWTl);
    k_init<<<1024, 256, 0, stream>>>(x, curh, curl,
                                     h0h[0], h0l[0], h0h[1], h0l[1],
                                     h1h[0], h1l[0], h1h[1], h1l[1], c0, c1, flags);

    float* lastcell = out + (size_t)B_ * (T_ - 1) * D_;

    KArgs a;
    a.x = x;
    a.wB0Th = wB0Th; a.wB0Tl = wB0Tl; a.wB1Th = wB1Th; a.wB1Tl = wB1Tl;
    a.wWTh = wWTh; a.wWTl = wWTl;
    a.b0 = b0; a.b1 = b1; a.bo = bo;
    a.curh = curh; a.curl = curl;
    a.h0h0 = h0h[0]; a.h0l0 = h0l[0]; a.h0h1 = h0h[1]; a.h0l1 = h0l[1];
    a.h1h0 = h1h[0]; a.h1l0 = h1l[0]; a.h1h1 = h1h[1]; a.h1l1 = h1l[1];
    a.c0 = c0; a.c1 = c1;
    a.outPred = out; a.lastcell = lastcell;
    a.flags = flags;

    void* kargs[] = { &a };
    hipLaunchCooperativeKernel((const void*)k_persistent, dim3(256), dim3(512),
                               kargs, 0, stream);
}

// Round 5
// 14317.079 us; speedup vs baseline: 4.1366x; 4.1366x over previous
//
#include <hip/hip_runtime.h>

#define B_ 512
#define T_ 256
#define D_ 128
#define H_ 512

typedef __bf16 bf16x8 __attribute__((ext_vector_type(8)));
typedef float f32x4 __attribute__((ext_vector_type(4)));
typedef unsigned long long u64;

__device__ __forceinline__ float sigm(float x) { return 1.f / (1.f + __expf(-x)); }
__device__ __forceinline__ float tanh_(float x) { return 2.f / (1.f + __expf(-2.f * x)) - 1.f; }

__device__ __forceinline__ void split2(float v, __bf16& hi, __bf16& lo) {
    hi = (__bf16)v;
    lo = (__bf16)(v - (float)hi);
}

__device__ __forceinline__ u64 cload(const __bf16* p) {
    return __hip_atomic_load((u64*)p, __ATOMIC_RELAXED, __HIP_MEMORY_SCOPE_AGENT);
}
__device__ __forceinline__ void cstore(__bf16* p, u64 v) {
    __hip_atomic_store((u64*)p, v, __ATOMIC_RELAXED, __HIP_MEMORY_SCOPE_AGENT);
}

// ---------------- weight convert: fp32 -> split bf16 (hi+lo), transposed to [N][K] ----------------
__global__ void k_convert(const float* __restrict__ k0, const float* __restrict__ r0,
                          const float* __restrict__ k1, const float* __restrict__ r1,
                          const float* __restrict__ W,
                          __bf16* __restrict__ wB0Th, __bf16* __restrict__ wB0Tl,  // [2048][640]
                          __bf16* __restrict__ wB1Th, __bf16* __restrict__ wB1Tl,  // [2048][1024]
                          __bf16* __restrict__ wWTh,  __bf16* __restrict__ wWTl)   // [128][512]
{
    int tid = blockIdx.x * blockDim.x + threadIdx.x;
    int nth = gridDim.x * blockDim.x;
    for (int idx = tid; idx < 640 * 2048; idx += nth) {
        int k = idx >> 11, n = idx & 2047;
        float v = (k < 128) ? k0[k * 2048 + n] : r0[(k - 128) * 2048 + n];
        split2(v, wB0Th[n * 640 + k], wB0Tl[n * 640 + k]);
    }
    for (int idx = tid; idx < 1024 * 2048; idx += nth) {
        int k = idx >> 11, n = idx & 2047;
        float v = (k < 512) ? k1[k * 2048 + n] : r1[(k - 512) * 2048 + n];
        split2(v, wB1Th[n * 1024 + k], wB1Tl[n * 1024 + k]);
    }
    for (int idx = tid; idx < 512 * 128; idx += nth) {
        int k = idx >> 7, n = idx & 127;
        split2(W[k * 128 + n], wWTh[n * 512 + k], wWTl[n * 512 + k]);
    }
}

// ---------------- init: cur = x[:,0,:] (split), zero h/c state, zero barrier counters --------
__global__ void k_init(const float* __restrict__ x,
                       __bf16* __restrict__ curh, __bf16* __restrict__ curl,
                       __bf16* __restrict__ h0ah, __bf16* __restrict__ h0al,
                       __bf16* __restrict__ h0bh, __bf16* __restrict__ h0bl,
                       __bf16* __restrict__ h1ah, __bf16* __restrict__ h1al,
                       __bf16* __restrict__ h1bh, __bf16* __restrict__ h1bl,
                       float* __restrict__ c0, float* __restrict__ c1,
                       int* __restrict__ cnt)
{
    int tid = blockIdx.x * blockDim.x + threadIdx.x;
    int nth = gridDim.x * blockDim.x;
    if (tid < 1024) cnt[tid] = 0;
    for (int idx = tid; idx < B_ * D_; idx += nth) {
        int b = idx >> 7, d = idx & 127;
        split2(x[b * (T_ * D_) + d], curh[idx], curl[idx]);  // t=0: missing stays 128.0 exactly
    }
    for (int idx = tid; idx < B_ * H_; idx += nth) {
        h0ah[idx] = (__bf16)0.f; h0al[idx] = (__bf16)0.f;
        h0bh[idx] = (__bf16)0.f; h0bl[idx] = (__bf16)0.f;
        h1ah[idx] = (__bf16)0.f; h1al[idx] = (__bf16)0.f;
        h1bh[idx] = (__bf16)0.f; h1bl[idx] = (__bf16)0.f;
        c0[idx] = 0.f; c1[idx] = 0.f;
    }
}

// ---------------- fence-free grid barrier: counter per epoch ----------------
// Release: each wave drains its own stores (vmcnt 0) before s_barrier; then one
// atomicAdd per WG. Acquire: data reads after the barrier use agent-scope
// coherent loads, so no cache invalidate is needed. No __threadfence -> L2
// (weights!) stays warm.
__device__ __forceinline__ void gbar(int* cnt, int k) {
    asm volatile("s_waitcnt vmcnt(0)" ::: "memory");
    __syncthreads();
    if (threadIdx.x == 0) {
        __hip_atomic_fetch_add(&cnt[k], 1, __ATOMIC_RELAXED, __HIP_MEMORY_SCOPE_AGENT);
        while (__hip_atomic_load(&cnt[k], __ATOMIC_RELAXED, __HIP_MEMORY_SCOPE_AGENT) < 256)
            __builtin_amdgcn_s_sleep(1);
    }
    __syncthreads();
}

// ---------------- one LSTM layer phase: z^T = (B^T)(A^T), gates, h,c ----------------
// Operand-swapped MFMA: lane holds one m-row (lane&15) and 4 consecutive j-cols
// ((lane>>4)*4+r) -> contiguous epilogue accesses. A (state) via coherent u64
// loads; B (weights) via normal cached loads. Prefetch depth 2.
template <int KTOT, int K1>
__device__ __forceinline__ void layer_phase(
    const __bf16* __restrict__ A1h, const __bf16* __restrict__ A1l, int lda1,
    const __bf16* __restrict__ A2h, const __bf16* __restrict__ A2l, int lda2,
    const __bf16* __restrict__ BTh, const __bf16* __restrict__ BTl,
    const float* __restrict__ bias,
    float* __restrict__ cst,
    __bf16* __restrict__ houth, __bf16* __restrict__ houtl,
    float* __restrict__ hout_f32,
    int j0, int m0,
    __bf16* sAh, __bf16* sAl, __bf16* sBh, __bf16* sBl, float* szred)
{
    constexpr int LSTR = 72;
    const int tid = threadIdx.x;
    const int lane = tid & 63;
    const int wave = tid >> 6;
    const int wpair = wave >> 1;
    const int ksub = wave & 1;

    const int srow = tid >> 3;
    const int skc = (tid & 7) << 3;
    const int bgrow = (srow >> 4) * 512 + j0 + (srow & 15);

    u64 rAh0[2], rAh1[2], rAl0[2], rAl1[2];
    uint4 rBh[2], rBl[2];

    auto loadA = [&](int kb, int s) {
        int k = kb + skc;
        const __bf16 *ah, *al; size_t off;
        if (k < K1) { ah = A1h; al = A1l; off = (size_t)(m0 + srow) * lda1 + k; }
        else        { ah = A2h; al = A2l; off = (size_t)(m0 + srow) * lda2 + (k - K1); }
        rAh0[s] = cload(ah + off);
        rAh1[s] = cload(ah + off + 4);
        rAl0[s] = cload(al + off);
        rAl1[s] = cload(al + off + 4);
    };
    auto loadB = [&](int kb, int s) {
        size_t off = (size_t)bgrow * KTOT + kb + skc;
        rBh[s] = *reinterpret_cast<const uint4*>(BTh + off);
        rBl[s] = *reinterpret_cast<const uint4*>(BTl + off);
    };

    loadA(0, 0); loadB(0, 0);
    loadA(64, 1); loadB(64, 1);

    f32x4 acc[4] = {};
    const int aidx = (wpair * 16 + (lane & 15)) * LSTR + ksub * 32 + ((lane >> 4) << 3);
    const int kf = ksub * 32 + ((lane >> 4) << 3);

    int s = 0;
    for (int kb = 0; kb < KTOT; kb += 64, s ^= 1) {
        __syncthreads();
        *(u64*)&sAh[srow * LSTR + skc]     = rAh0[s];
        *(u64*)&sAh[srow * LSTR + skc + 4] = rAh1[s];
        *(u64*)&sAl[srow * LSTR + skc]     = rAl0[s];
        *(u64*)&sAl[srow * LSTR + skc + 4] = rAl1[s];
        *(uint4*)&sBh[srow * LSTR + skc] = rBh[s];
        *(uint4*)&sBl[srow * LSTR + skc] = rBl[s];
        if (kb + 128 < KTOT) { loadA(kb + 128, s); loadB(kb + 128, s); }
        __syncthreads();
        bf16x8 a_h = *reinterpret_cast<const bf16x8*>(&sAh[aidx]);
        bf16x8 a_l = *reinterpret_cast<const bf16x8*>(&sAl[aidx]);
#pragma unroll
        for (int g = 0; g < 4; ++g) {
            int bi = (g * 16 + (lane & 15)) * LSTR + kf;
            bf16x8 b_h = *reinterpret_cast<const bf16x8*>(&sBh[bi]);
            bf16x8 b_l = *reinterpret_cast<const bf16x8*>(&sBl[bi]);
            // swapped operands: acc holds z^T fragment
            acc[g] = __builtin_amdgcn_mfma_f32_16x16x32_bf16(b_h, a_h, acc[g], 0, 0, 0);
            acc[g] = __builtin_amdgcn_mfma_f32_16x16x32_bf16(b_l, a_h, acc[g], 0, 0, 0);
            acc[g] = __builtin_amdgcn_mfma_f32_16x16x32_bf16(b_h, a_l, acc[g], 0, 0, 0);
        }
    }

    if (ksub == 1) {
#pragma unroll
        for (int g = 0; g < 4; ++g)
            *reinterpret_cast<f32x4*>(&szred[(wpair * 64 + lane) * 20 + g * 4]) = acc[g];
    }
    __syncthreads();
    if (ksub == 0) {
        const int row  = m0 + wpair * 16 + (lane & 15);
        const int colb = j0 + ((lane >> 4) << 2);
        const float* zr = &szred[(wpair * 64 + lane) * 20];
        f32x4 bi4 = *reinterpret_cast<const f32x4*>(&bias[colb]);
        f32x4 bf4 = *reinterpret_cast<const f32x4*>(&bias[512 + colb]);
        f32x4 bg4 = *reinterpret_cast<const f32x4*>(&bias[1024 + colb]);
        f32x4 bo4 = *reinterpret_cast<const f32x4*>(&bias[1536 + colb]);
        f32x4 c4 = *reinterpret_cast<f32x4*>(&cst[row * H_ + colb]);
        union { __bf16 b[4]; u64 u; } hh, hl;
        f32x4 h4;
#pragma unroll
        for (int r = 0; r < 4; ++r) {
            float zi = acc[0][r] + zr[0 + r] + bi4[r];
            float zf = acc[1][r] + zr[4 + r] + bf4[r];
            float zg = acc[2][r] + zr[8 + r] + bg4[r];
            float zo = acc[3][r] + zr[12 + r] + bo4[r];
            float gi = sigm(zi), gf = sigm(zf), gg = tanh_(zg), go = sigm(zo);
            float c = gf * c4[r] + gi * gg;
            c4[r] = c;
            float h = go * tanh_(c);
            h4[r] = h;
            split2(h, hh.b[r], hl.b[r]);
        }
        *reinterpret_cast<f32x4*>(&cst[row * H_ + colb]) = c4;
        cstore(&houth[row * H_ + colb], hh.u);
        cstore(&houtl[row * H_ + colb], hl.u);
        if (hout_f32) *reinterpret_cast<f32x4*>(&hout_f32[row * H_ + colb]) = h4;
    }
}

// ---------------- pred phase: one 16x16 tile/WG, 8-wave K-split, LDS reduce ----------------
__device__ __forceinline__ void pred_phase(
    const __bf16* __restrict__ h1ph, const __bf16* __restrict__ h1pl,
    const __bf16* __restrict__ WTh, const __bf16* __restrict__ WTl,
    const float* __restrict__ bout, const float* __restrict__ x, int t,
    __bf16* __restrict__ curh, __bf16* __restrict__ curl,
    float* __restrict__ outPred, int wg, float* sred)
{
    const int tid = threadIdx.x;
    const int wave = tid >> 6, l = tid & 63;
    const int pr = wg >> 3;          // b-row tile 0..31
    const int pc = wg & 7;           // d-col tile 0..7
    const int arow = (pr * 16 + (l & 15)) * 512;   // h1 row base
    const int brow = (pc * 16 + (l & 15)) * 512;   // WT row base
    const int kof = ((l >> 4) << 3);

    union U8 { u64 u[2]; bf16x8 v; };
    union Q8 { uint4 q; bf16x8 v; };

    f32x4 acc = {};
#pragma unroll
    for (int ki = 0; ki < 2; ++ki) {
        int k = wave * 64 + ki * 32 + kof;
        U8 ah, al; Q8 bh, bl;
        ah.u[0] = cload(h1ph + arow + k); ah.u[1] = cload(h1ph + arow + k + 4);
        al.u[0] = cload(h1pl + arow + k); al.u[1] = cload(h1pl + arow + k + 4);
        bh.q = *reinterpret_cast<const uint4*>(WTh + brow + k);
        bl.q = *reinterpret_cast<const uint4*>(WTl + brow + k);
        // swapped: lane holds b=pr*16+(l&15), d=pc*16+(l>>4)*4+r
        acc = __builtin_amdgcn_mfma_f32_16x16x32_bf16(bh.v, ah.v, acc, 0, 0, 0);
        acc = __builtin_amdgcn_mfma_f32_16x16x32_bf16(bl.v, ah.v, acc, 0, 0, 0);
        acc = __builtin_amdgcn_mfma_f32_16x16x32_bf16(bh.v, al.v, acc, 0, 0, 0);
    }
    *reinterpret_cast<f32x4*>(&sred[(wave * 64 + l) * 4]) = acc;
    __syncthreads();
    if (wave == 0) {
#pragma unroll
        for (int w = 1; w < 8; ++w)
            acc += *reinterpret_cast<const f32x4*>(&sred[(w * 64 + l) * 4]);
        const int b = pr * 16 + (l & 15);
        const int colb = pc * 16 + ((l >> 4) << 2);
        f32x4 bo4 = *reinterpret_cast<const f32x4*>(&bout[colb]);
        f32x4 xv4 = *reinterpret_cast<const f32x4*>(&x[((size_t)b * T_ + t) * D_ + colb]);
        f32x4 p4;
        union { __bf16 bb[4]; u64 u; } ch, cl;
#pragma unroll
        for (int r = 0; r < 4; ++r) {
            float pred = acc[r] + bo4[r];
            p4[r] = pred;
            float cv = (xv4[r] == 128.0f) ? pred : xv4[r];
            split2(cv, ch.bb[r], cl.bb[r]);
        }
        *reinterpret_cast<f32x4*>(&outPred[((size_t)b * (T_ - 1) + (t - 1)) * D_ + colb]) = p4;
        cstore(&curh[b * D_ + colb], ch.u);
        cstore(&curl[b * D_ + colb], cl.u);
    }
}

// ---------------- persistent kernel: whole T-loop, fence-free barriers ----------------
struct KArgs {
    const float* x;
    const __bf16 *wB0Th, *wB0Tl, *wB1Th, *wB1Tl, *wWTh, *wWTl;
    const float *b0, *b1, *bo;
    __bf16 *curh, *curl;
    __bf16 *h0h0, *h0l0, *h0h1, *h0l1;
    __bf16 *h1h0, *h1l0, *h1h1, *h1l1;
    float *c0, *c1;
    float *outPred, *lastcell;
    int* cnt;
};

__global__ __launch_bounds__(512) void k_persistent(KArgs a)
{
    __shared__ __align__(16) __bf16 sAh[64 * 72], sAl[64 * 72];
    __shared__ __align__(16) __bf16 sBh[64 * 72], sBl[64 * 72];
    __shared__ __align__(16) float szred[4 * 64 * 20];

    const int wg = blockIdx.x;
    const int j0 = (wg & 31) * 16;
    const int m0 = (wg >> 5) * 64;

    __bf16* h0h[2] = { a.h0h0, a.h0h1 };
    __bf16* h0l[2] = { a.h0l0, a.h0l1 };
    __bf16* h1h[2] = { a.h1h0, a.h1h1 };
    __bf16* h1l[2] = { a.h1l0, a.h1l1 };

    int bk = 0;
    for (int t = 0; t < T_; ++t) {
        int cu = t & 1, pv = cu ^ 1;
        if (t > 0) {
            pred_phase(h1h[pv], h1l[pv], a.wWTh, a.wWTl, a.bo, a.x, t,
                       a.curh, a.curl, a.outPred, wg, szred);
            gbar(a.cnt, ++bk);
        }
        layer_phase<640, 128>(a.curh, a.curl, D_, h0h[pv], h0l[pv], H_,
                              a.wB0Th, a.wB0Tl, a.b0, a.c0,
                              h0h[cu], h0l[cu], nullptr, j0, m0,
                              sAh, sAl, sBh, sBl, szred);
        gbar(a.cnt, ++bk);
        layer_phase<1024, 512>(h0h[cu], h0l[cu], H_, h1h[pv], h1l[pv], H_,
                               a.wB1Th, a.wB1Tl, a.b1, a.c1,
                               h1h[cu], h1l[cu],
                               (t == T_ - 1) ? a.lastcell : nullptr, j0, m0,
                               sAh, sAl, sBh, sBl, szred);
        gbar(a.cnt, ++bk);
    }
}

extern "C" void kernel_launch(void* const* d_in, const int* in_sizes, int n_in,
                              void* d_out, int out_size, void* d_ws, size_t ws_size,
                              hipStream_t stream)
{
    const float* x  = (const float*)d_in[0];
    const float* k0 = (const float*)d_in[1];
    const float* r0 = (const float*)d_in[2];
    const float* b0 = (const float*)d_in[3];
    const float* k1 = (const float*)d_in[4];
    const float* r1 = (const float*)d_in[5];
    const float* b1 = (const float*)d_in[6];
    const float* W  = (const float*)d_in[7];
    const float* bo = (const float*)d_in[8];
    float* out = (float*)d_out;

    char* ws = (char*)d_ws;
    size_t off = 0;
    auto alloc = [&](size_t bytes) { void* p = ws + off; off += (bytes + 255) & ~255ull; return p; };
    __bf16* wB0Th = (__bf16*)alloc((size_t)2048 * 640 * 2);
    __bf16* wB0Tl = (__bf16*)alloc((size_t)2048 * 640 * 2);
    __bf16* wB1Th = (__bf16*)alloc((size_t)2048 * 1024 * 2);
    __bf16* wB1Tl = (__bf16*)alloc((size_t)2048 * 1024 * 2);
    __bf16* wWTh  = (__bf16*)alloc((size_t)128 * 512 * 2);
    __bf16* wWTl  = (__bf16*)alloc((size_t)128 * 512 * 2);
    __bf16* curh  = (__bf16*)alloc((size_t)B_ * D_ * 2);
    __bf16* curl  = (__bf16*)alloc((size_t)B_ * D_ * 2);
    __bf16* h0h[2] = { (__bf16*)alloc((size_t)B_ * H_ * 2), (__bf16*)alloc((size_t)B_ * H_ * 2) };
    __bf16* h0l[2] = { (__bf16*)alloc((size_t)B_ * H_ * 2), (__bf16*)alloc((size_t)B_ * H_ * 2) };
    __bf16* h1h[2] = { (__bf16*)alloc((size_t)B_ * H_ * 2), (__bf16*)alloc((size_t)B_ * H_ * 2) };
    __bf16* h1l[2] = { (__bf16*)alloc((size_t)B_ * H_ * 2), (__bf16*)alloc((size_t)B_ * H_ * 2) };
    float* c0 = (float*)alloc((size_t)B_ * H_ * 4);
    float* c1 = (float*)alloc((size_t)B_ * H_ * 4);
    int* cnt = (int*)alloc(1024 * sizeof(int));

    k_convert<<<2048, 256, 0, stream>>>(k0, r0, k1, r1, W, wB0Th, wB0Tl, wB1Th, wB1Tl, wWTh, wWTl);
    k_init<<<1024, 256, 0, stream>>>(x, curh, curl,
                                     h0h[0], h0l[0], h0h[1], h0l[1],
                                     h1h[0], h1l[0], h1h[1], h1l[1], c0, c1, cnt);

    float* lastcell = out + (size_t)B_ * (T_ - 1) * D_;

    KArgs a;
    a.x = x;
    a.wB0Th = wB0Th; a.wB0Tl = wB0Tl; a.wB1Th = wB1Th; a.wB1Tl = wB1Tl;
    a.wWTh = wWTh; a.wWTl = wWTl;
    a.b0 = b0; a.b1 = b1; a.bo = bo;
    a.curh = curh; a.curl = curl;
    a.h0h0 = h0h[0]; a.h0l0 = h0l[0]; a.h0h1 = h0h[1]; a.h0l1 = h0l[1];
    a.h1h0 = h1h[0]; a.h1l0 = h1l[0]; a.h1h1 = h1h[1]; a.h1l1 = h1l[1];
    a.c0 = c0; a.c1 = c1;
    a.outPred = out; a.lastcell = lastcell;
    a.cnt = cnt;

    void* kargs[] = { &a };
    hipLaunchCooperativeKernel((const void*)k_persistent, dim3(256), dim3(512),
                               kargs, 0, stream);
}

// Round 6
// 7577.859 us; speedup vs baseline: 7.8154x; 1.8893x over previous
//
#include <hip/hip_runtime.h>

#define B_ 512
#define T_ 256
#define D_ 128
#define H_ 512

typedef __bf16 bf16x8 __attribute__((ext_vector_type(8)));
typedef float f32x4 __attribute__((ext_vector_type(4)));
typedef unsigned long long u64;

__device__ __forceinline__ float sigm(float x) { return 1.f / (1.f + __expf(-x)); }
__device__ __forceinline__ float tanh_(float x) { return 2.f / (1.f + __expf(-2.f * x)) - 1.f; }

__device__ __forceinline__ void split2(float v, __bf16& hi, __bf16& lo) {
    hi = (__bf16)v;
    lo = (__bf16)(v - (float)hi);
}

// ---------------- weight convert: fp32 -> split bf16 (hi+lo), transposed to [N][K] ----------------
__global__ void k_convert(const float* __restrict__ k0, const float* __restrict__ r0,
                          const float* __restrict__ k1, const float* __restrict__ r1,
                          const float* __restrict__ W,
                          __bf16* __restrict__ wB0Th, __bf16* __restrict__ wB0Tl,  // [2048][640]
                          __bf16* __restrict__ wB1Th, __bf16* __restrict__ wB1Tl,  // [2048][1024]
                          __bf16* __restrict__ wWTh,  __bf16* __restrict__ wWTl)   // [128][512]
{
    int tid = blockIdx.x * blockDim.x + threadIdx.x;
    int nth = gridDim.x * blockDim.x;
    for (int idx = tid; idx < 640 * 2048; idx += nth) {
        int k = idx >> 11, n = idx & 2047;
        float v = (k < 128) ? k0[k * 2048 + n] : r0[(k - 128) * 2048 + n];
        split2(v, wB0Th[n * 640 + k], wB0Tl[n * 640 + k]);
    }
    for (int idx = tid; idx < 1024 * 2048; idx += nth) {
        int k = idx >> 11, n = idx & 2047;
        float v = (k < 512) ? k1[k * 2048 + n] : r1[(k - 512) * 2048 + n];
        split2(v, wB1Th[n * 1024 + k], wB1Tl[n * 1024 + k]);
    }
    for (int idx = tid; idx < 512 * 128; idx += nth) {
        int k = idx >> 7, n = idx & 127;
        split2(W[k * 128 + n], wWTh[n * 512 + k], wWTl[n * 512 + k]);
    }
}

// ---------------- init: cur = x[:,0,:] (split), zero h/c state ----------------
__global__ void k_init(const float* __restrict__ x,
                       __bf16* __restrict__ curh, __bf16* __restrict__ curl,
                       __bf16* __restrict__ h0ah, __bf16* __restrict__ h0al,
                       __bf16* __restrict__ h0bh, __bf16* __restrict__ h0bl,
                       __bf16* __restrict__ h1ah, __bf16* __restrict__ h1al,
                       __bf16* __restrict__ h1bh, __bf16* __restrict__ h1bl,
                       float* __restrict__ c0, float* __restrict__ c1)
{
    int tid = blockIdx.x * blockDim.x + threadIdx.x;
    int nth = gridDim.x * blockDim.x;
    for (int idx = tid; idx < B_ * D_; idx += nth) {
        int b = idx >> 7, d = idx & 127;
        split2(x[b * (T_ * D_) + d], curh[idx], curl[idx]);  // t=0: missing stays 128.0 exactly
    }
    for (int idx = tid; idx < B_ * H_; idx += nth) {
        h0ah[idx] = (__bf16)0.f; h0al[idx] = (__bf16)0.f;
        h0bh[idx] = (__bf16)0.f; h0bl[idx] = (__bf16)0.f;
        h1ah[idx] = (__bf16)0.f; h1al[idx] = (__bf16)0.f;
        h1bh[idx] = (__bf16)0.f; h1bl[idx] = (__bf16)0.f;
        c0[idx] = 0.f; c1[idx] = 0.f;
    }
}

// ---------------- one LSTM layer step, split GEMM, BK=128, swizzled LDS ----------------
// z^T fragments via swapped-operand MFMA (r5-verified): lane owns row m0+wpair*16+(lane&15),
// 4 consecutive cols j0+(lane>>4)*4..+3. A=[A1|A2] K-segments hi/lo; BT [2048][KTOT] hi/lo.
// 8 waves: wpair=wave>>1 (16-row group), ksub=wave&1 (K-half of each 128 tile).
// LDS: 4 tiles [64][144] bf16, 8-elem-block XOR swizzle (k ^ ((row&7)<<3)) -> 2-way banks.
template <int KTOT, int K1>
__global__ __launch_bounds__(512) void k_layer(
    const __bf16* __restrict__ A1h, const __bf16* __restrict__ A1l, int lda1,
    const __bf16* __restrict__ A2h, const __bf16* __restrict__ A2l, int lda2,
    const __bf16* __restrict__ BTh, const __bf16* __restrict__ BTl,
    const float* __restrict__ bias,       // [2048] gate order i,f,g,o
    float* __restrict__ cst,              // [512][512] fp32 rmw
    __bf16* __restrict__ houth, __bf16* __restrict__ houtl,
    float* __restrict__ hout_f32)         // optional fp32 copy (last_cell)
{
    constexpr int LSTR = 144;
    __shared__ __align__(16) char smem[4 * 64 * LSTR * 2];   // 73728 B
    __bf16* sAh = (__bf16*)smem;
    __bf16* sAl = sAh + 64 * LSTR;
    __bf16* sBh = sAl + 64 * LSTR;
    __bf16* sBl = sBh + 64 * LSTR;
    float* szred = (float*)smem;          // aliased over sAh+ after main loop (barrier-separated)

    const int j0 = blockIdx.x * 16;
    const int m0 = blockIdx.y * 64;
    const int tid = threadIdx.x;
    const int lane = tid & 63;
    const int wave = tid >> 6;
    const int wpair = wave >> 1;
    const int ksub = wave & 1;

    // staging: thread -> (row, 16-elem k chunk)
    const int srow = tid >> 3;
    const int skc = (tid & 7) << 4;       // 0,16,...,112
    const int swz = (srow & 7) << 3;
    const int sw1 = srow * LSTR + (skc ^ swz);
    const int sw2 = srow * LSTR + ((skc + 8) ^ swz);
    const int bgrow = (srow >> 4) * 512 + j0 + (srow & 15);

    uint4 rA0, rA1, rAl0, rAl1, rB0, rB1, rBl0, rBl1;
    auto loadA = [&](int kb) {
        int k = kb + skc;
        const __bf16 *ah, *al; size_t off;
        if (k < K1) { ah = A1h; al = A1l; off = (size_t)(m0 + srow) * lda1 + k; }
        else        { ah = A2h; al = A2l; off = (size_t)(m0 + srow) * lda2 + (k - K1); }
        rA0 = *reinterpret_cast<const uint4*>(ah + off);
        rA1 = *reinterpret_cast<const uint4*>(ah + off + 8);
        rAl0 = *reinterpret_cast<const uint4*>(al + off);
        rAl1 = *reinterpret_cast<const uint4*>(al + off + 8);
    };
    auto loadB = [&](int kb) {
        size_t off = (size_t)bgrow * KTOT + kb + skc;
        rB0 = *reinterpret_cast<const uint4*>(BTh + off);
        rB1 = *reinterpret_cast<const uint4*>(BTh + off + 8);
        rBl0 = *reinterpret_cast<const uint4*>(BTl + off);
        rBl1 = *reinterpret_cast<const uint4*>(BTl + off + 8);
    };

    loadA(0); loadB(0);

    f32x4 acc[4] = {};
    const int arow = wpair * 16 + (lane & 15);
    const int abase = arow * LSTR;
    const int aswz = (arow & 7) << 3;
    const int kfrag = ksub * 64 + ((lane >> 4) << 3);

    for (int kb = 0; kb < KTOT; kb += 128) {
        __syncthreads();
        *reinterpret_cast<uint4*>(&sAh[sw1]) = rA0;
        *reinterpret_cast<uint4*>(&sAh[sw2]) = rA1;
        *reinterpret_cast<uint4*>(&sAl[sw1]) = rAl0;
        *reinterpret_cast<uint4*>(&sAl[sw2]) = rAl1;
        *reinterpret_cast<uint4*>(&sBh[sw1]) = rB0;
        *reinterpret_cast<uint4*>(&sBh[sw2]) = rB1;
        *reinterpret_cast<uint4*>(&sBl[sw1]) = rBl0;
        *reinterpret_cast<uint4*>(&sBl[sw2]) = rBl1;
        if (kb + 128 < KTOT) { loadA(kb + 128); loadB(kb + 128); }
        __syncthreads();
#pragma unroll
        for (int kk = 0; kk < 2; ++kk) {
            int ko = kfrag + kk * 32;
            int ai = abase + (ko ^ aswz);
            bf16x8 a_h = *reinterpret_cast<const bf16x8*>(&sAh[ai]);
            bf16x8 a_l = *reinterpret_cast<const bf16x8*>(&sAl[ai]);
#pragma unroll
            for (int g = 0; g < 4; ++g) {
                int brow = g * 16 + (lane & 15);
                int bi = brow * LSTR + (ko ^ ((brow & 7) << 3));
                bf16x8 b_h = *reinterpret_cast<const bf16x8*>(&sBh[bi]);
                bf16x8 b_l = *reinterpret_cast<const bf16x8*>(&sBl[bi]);
                acc[g] = __builtin_amdgcn_mfma_f32_16x16x32_bf16(b_h, a_h, acc[g], 0, 0, 0);
                acc[g] = __builtin_amdgcn_mfma_f32_16x16x32_bf16(b_l, a_h, acc[g], 0, 0, 0);
                acc[g] = __builtin_amdgcn_mfma_f32_16x16x32_bf16(b_h, a_l, acc[g], 0, 0, 0);
            }
        }
    }

    __syncthreads();                      // staging reads done; szred may alias
    if (ksub == 1) {
        float* zr = &szred[(wpair * 64 + lane) * 21];
#pragma unroll
        for (int g = 0; g < 4; ++g)
#pragma unroll
            for (int r = 0; r < 4; ++r)
                zr[g * 4 + r] = acc[g][r];
    }
    __syncthreads();
    if (ksub == 0) {
        const int row  = m0 + wpair * 16 + (lane & 15);
        const int colb = j0 + ((lane >> 4) << 2);
        const float* zr = &szred[(wpair * 64 + lane) * 21];
        f32x4 bi4 = *reinterpret_cast<const f32x4*>(&bias[colb]);
        f32x4 bf4 = *reinterpret_cast<const f32x4*>(&bias[512 + colb]);
        f32x4 bg4 = *reinterpret_cast<const f32x4*>(&bias[1024 + colb]);
        f32x4 bo4 = *reinterpret_cast<const f32x4*>(&bias[1536 + colb]);
        f32x4 c4 = *reinterpret_cast<f32x4*>(&cst[row * H_ + colb]);
        union { __bf16 b[4]; u64 u; } hh, hl;
        f32x4 h4;
#pragma unroll
        for (int r = 0; r < 4; ++r) {
            float zi = acc[0][r] + zr[0 + r] + bi4[r];
            float zf = acc[1][r] + zr[4 + r] + bf4[r];
            float zg = acc[2][r] + zr[8 + r] + bg4[r];
            float zo = acc[3][r] + zr[12 + r] + bo4[r];
            float gi = sigm(zi), gf = sigm(zf), gg = tanh_(zg), go = sigm(zo);
            float c = gf * c4[r] + gi * gg;
            c4[r] = c;
            float h = go * tanh_(c);
            h4[r] = h;
            split2(h, hh.b[r], hl.b[r]);
        }
        *reinterpret_cast<f32x4*>(&cst[row * H_ + colb]) = c4;
        *reinterpret_cast<u64*>(&houth[row * H_ + colb]) = hh.u;
        *reinterpret_cast<u64*>(&houtl[row * H_ + colb]) = hl.u;
        if (hout_f32) *reinterpret_cast<f32x4*>(&hout_f32[row * H_ + colb]) = h4;
    }
}

// ---------------- pred: one 16x16 tile/WG, 8-wave K-split, direct frag loads ----------------
// Grid 256 WGs (32 b-row tiles x 8 d-col tiles), 512 threads.
__global__ __launch_bounds__(512) void k_pred(
    const __bf16* __restrict__ h1ph, const __bf16* __restrict__ h1pl,  // [512][512]
    const __bf16* __restrict__ WTh, const __bf16* __restrict__ WTl,    // [128][512]
    const float* __restrict__ bout,
    const float* __restrict__ x,         // [512][256][128]
    int t,
    __bf16* __restrict__ curh, __bf16* __restrict__ curl,  // [512][128]
    float* __restrict__ outPred)         // [B*(T-1)][128] region of d_out
{
    __shared__ float sred[512 * 5];

    const int tid = threadIdx.x;
    const int wave = tid >> 6, l = tid & 63;
    const int pr = blockIdx.x >> 3;       // b-row tile 0..31
    const int pc = blockIdx.x & 7;        // d-col tile 0..7
    const int arow = (pr * 16 + (l & 15)) * 512;
    const int brow = (pc * 16 + (l & 15)) * 512;
    const int kof = (l >> 4) << 3;

    f32x4 acc = {};
#pragma unroll
    for (int kk = 0; kk < 2; ++kk) {
        int k = wave * 64 + kk * 32 + kof;
        bf16x8 ah = *reinterpret_cast<const bf16x8*>(h1ph + arow + k);
        bf16x8 al = *reinterpret_cast<const bf16x8*>(h1pl + arow + k);
        bf16x8 bh = *reinterpret_cast<const bf16x8*>(WTh + brow + k);
        bf16x8 bl = *reinterpret_cast<const bf16x8*>(WTl + brow + k);
        // swapped: lane holds b=pr*16+(l&15), d=pc*16+(l>>4)*4+r
        acc = __builtin_amdgcn_mfma_f32_16x16x32_bf16(bh, ah, acc, 0, 0, 0);
        acc = __builtin_amdgcn_mfma_f32_16x16x32_bf16(bl, ah, acc, 0, 0, 0);
        acc = __builtin_amdgcn_mfma_f32_16x16x32_bf16(bh, al, acc, 0, 0, 0);
    }
    {
        float* sr = &sred[(wave * 64 + l) * 5];
#pragma unroll
        for (int r = 0; r < 4; ++r) sr[r] = acc[r];
    }
    __syncthreads();
    if (wave == 0) {
#pragma unroll
        for (int w = 1; w < 8; ++w) {
            const float* sr = &sred[(w * 64 + l) * 5];
#pragma unroll
            for (int r = 0; r < 4; ++r) acc[r] += sr[r];
        }
        const int b = pr * 16 + (l & 15);
        const int colb = pc * 16 + ((l >> 4) << 2);
        f32x4 bo4 = *reinterpret_cast<const f32x4*>(&bout[colb]);
        f32x4 xv4 = *reinterpret_cast<const f32x4*>(&x[((size_t)b * T_ + t) * D_ + colb]);
        f32x4 p4;
        union { __bf16 bb[4]; u64 u; } ch, cl;
#pragma unroll
        for (int r = 0; r < 4; ++r) {
            float pred = acc[r] + bo4[r];
            p4[r] = pred;
            float cv = (xv4[r] == 128.0f) ? pred : xv4[r];
            split2(cv, ch.bb[r], cl.bb[r]);
        }
        *reinterpret_cast<f32x4*>(&outPred[((size_t)b * (T_ - 1) + (t - 1)) * D_ + colb]) = p4;
        *reinterpret_cast<u64*>(&curh[b * D_ + colb]) = ch.u;
        *reinterpret_cast<u64*>(&curl[b * D_ + colb]) = cl.u;
    }
}

extern "C" void kernel_launch(void* const* d_in, const int* in_sizes, int n_in,
                              void* d_out, int out_size, void* d_ws, size_t ws_size,
                              hipStream_t stream)
{
    const float* x  = (const float*)d_in[0];
    const float* k0 = (const float*)d_in[1];
    const float* r0 = (const float*)d_in[2];
    const float* b0 = (const float*)d_in[3];
    const float* k1 = (const float*)d_in[4];
    const float* r1 = (const float*)d_in[5];
    const float* b1 = (const float*)d_in[6];
    const float* W  = (const float*)d_in[7];
    const float* bo = (const float*)d_in[8];
    float* out = (float*)d_out;

    char* ws = (char*)d_ws;
    size_t off = 0;
    auto alloc = [&](size_t bytes) { void* p = ws + off; off += (bytes + 255) & ~255ull; return p; };
    __bf16* wB0Th = (__bf16*)alloc((size_t)2048 * 640 * 2);
    __bf16* wB0Tl = (__bf16*)alloc((size_t)2048 * 640 * 2);
    __bf16* wB1Th = (__bf16*)alloc((size_t)2048 * 1024 * 2);
    __bf16* wB1Tl = (__bf16*)alloc((size_t)2048 * 1024 * 2);
    __bf16* wWTh  = (__bf16*)alloc((size_t)128 * 512 * 2);
    __bf16* wWTl  = (__bf16*)alloc((size_t)128 * 512 * 2);
    __bf16* curh  = (__bf16*)alloc((size_t)B_ * D_ * 2);
    __bf16* curl  = (__bf16*)alloc((size_t)B_ * D_ * 2);
    __bf16* h0h[2] = { (__bf16*)alloc((size_t)B_ * H_ * 2), (__bf16*)alloc((size_t)B_ * H_ * 2) };
    __bf16* h0l[2] = { (__bf16*)alloc((size_t)B_ * H_ * 2), (__bf16*)alloc((size_t)B_ * H_ * 2) };
    __bf16* h1h[2] = { (__bf16*)alloc((size_t)B_ * H_ * 2), (__bf16*)alloc((size_t)B_ * H_ * 2) };
    __bf16* h1l[2] = { (__bf16*)alloc((size_t)B_ * H_ * 2), (__bf16*)alloc((size_t)B_ * H_ * 2) };
    float* c0 = (float*)alloc((size_t)B_ * H_ * 4);
    float* c1 = (float*)alloc((size_t)B_ * H_ * 4);

    k_convert<<<2048, 256, 0, stream>>>(k0, r0, k1, r1, W, wB0Th, wB0Tl, wB1Th, wB1Tl, wWTh, wWTl);
    k_init<<<1024, 256, 0, stream>>>(x, curh, curl,
                                     h0h[0], h0l[0], h0h[1], h0l[1],
                                     h1h[0], h1l[0], h1h[1], h1l[1], c0, c1);

    float* lastcell = out + (size_t)B_ * (T_ - 1) * D_;

    for (int t = 0; t < T_; ++t) {
        int cu = t & 1, pv = cu ^ 1;
        if (t > 0)
            k_pred<<<256, 512, 0, stream>>>(h1h[pv], h1l[pv], wWTh, wWTl, bo, x, t,
                                            curh, curl, out);
        k_layer<640, 128><<<dim3(32, 8), 512, 0, stream>>>(
            curh, curl, D_, h0h[pv], h0l[pv], H_, wB0Th, wB0Tl, b0, c0,
            h0h[cu], h0l[cu], nullptr);
        k_layer<1024, 512><<<dim3(32, 8), 512, 0, stream>>>(
            h0h[cu], h0l[cu], H_, h1h[pv], h1l[pv], H_, wB1Th, wB1Tl, b1, c1,
            h1h[cu], h1l[cu], (t == T_ - 1) ? lastcell : nullptr);
    }
}